// Round 3
// baseline (155.848 us; speedup 1.0000x reference)
//
#include <hip/hip_runtime.h>

#define NTAG 64
#define TLEN 512
#define START_TAG 62
#define STOP_TAG 63
#define NB 16            // batch columns per tile (one fwd wave + one bwd wave)

typedef __attribute__((ext_vector_type(4))) float    f32x4;
typedef __attribute__((ext_vector_type(8))) short    s16x8;   // 8 bf16 bits
typedef __attribute__((ext_vector_type(2))) unsigned u32x2;
typedef __attribute__((ext_vector_type(4))) unsigned u32x4;

#if __has_builtin(__builtin_amdgcn_exp2f)
#define EXP2(x) __builtin_amdgcn_exp2f(x)
#else
#define EXP2(x) exp2f(x)
#endif

// v_cvt_pk_bf16_f32: D.lo = bf16(S0), D.hi = bf16(S1)  (guide T12, m240)
__device__ __forceinline__ unsigned cvtpk_bf16(float lo, float hi) {
    unsigned r;
    asm("v_cvt_pk_bf16_f32 %0, %1, %2" : "=v"(r) : "v"(lo), "v"(hi));
    return r;
}

// gfx950-verified builtin (m89/m92/m97). C/D: col=lane&15, row=4*(lane>>4)+reg.
__device__ __forceinline__ f32x4 mfma32(s16x8 a, s16x8 b, f32x4 c) {
    return __builtin_amdgcn_mfma_f32_16x16x32_bf16(a, b, c, 0, 0, 0);
}

// One wave-pair per 16-batch tile; state X (64 tags x 16 batches) lives in 8
// VGPRs as 4 packed dwords-pairs Bf[m] (rows 16m+4g+{0..3}, col c — exactly
// the m89 D layout). The next step's B operand is the CONCATENATION of these
// dwords under a self-chosen slot->k bijection rho(kt,g,jj) =
// 32kt+16*(jj>>2)+4g+(jj&3); the A fragments are built as E[r][rho(slot)],
// so the MFMA contracts correctly for ANY hardware slot->k map shared by A
// and B (all CDNA 16x16 shapes). Zero per-step repack; only the m89-verified
// C/D layout is assumed. Renorm: column-max pow2 rescale (layout-proof,
// never a structurally-zero reference).
__global__ __launch_bounds__(128) void crf_fwd_bwd(
    const float* __restrict__ emis,   // [512, 512, 64] f32
    const float* __restrict__ trans,  // [64, 64] f32, trans[next, prev]
    float* __restrict__ out)          // [512] f32
{
    const int tile = blockIdx.x;
    const int tid  = threadIdx.x;
    const int lane = tid & 63;
    const int w    = tid >> 6;      // 0 = fwd (t=0..255), 1 = bwd (t=511..256)
    const int c    = lane & 15;     // batch column within tile
    const int g    = lane >> 4;     // 4-row group
    const int b0   = tile * NB;

    const float L2E = 1.4426950408889634f;
    const float LN2 = 0.6931471805599453f;

    __shared__ float fy[64][17];    // bwd final beta (f32), +1 pad col
    __shared__ int   offb_sh[16];   // bwd pow2 offset per column

    // A fragments with baked permutation: slot jj of tile (m, kt) holds
    // E[16m+c][rho] (fwd) or E^T -> exp(trans[rho][16m+c]) (bwd), where
    // rho = 32kt + 16*(jj>>2) + 4g + (jj&3). Masked (-10000) -> exactly 0.
    s16x8 Af[4][2];
    #pragma unroll
    for (int m = 0; m < 4; ++m) {
        #pragma unroll
        for (int kt = 0; kt < 2; ++kt) {
            float ev[8];
            #pragma unroll
            for (int jj = 0; jj < 8; ++jj) {
                const int r = 16 * m + c;
                const int k = 32 * kt + 16 * (jj >> 2) + 4 * g + (jj & 3);
                const float tv = (w == 0) ? trans[r * NTAG + k]
                                          : trans[k * NTAG + r];
                ev[jj] = EXP2(tv * L2E);
            }
            u32x4 p;
            p[0] = cvtpk_bf16(ev[0], ev[1]);
            p[1] = cvtpk_bf16(ev[2], ev[3]);
            p[2] = cvtpk_bf16(ev[4], ev[5]);
            p[3] = cvtpk_bf16(ev[6], ev[7]);
            Af[m][kt] = __builtin_bit_cast(s16x8, p);
        }
    }

    const float* ebase = emis + (size_t)(b0 + c) * (TLEN * NTAG);

    u32x2  Bf[4];       // state: rows 16m+4g+{0..3} packed bf16 (8 VGPRs)
    f32x4  ym[4];       // current step f32 outputs (kept for the final dot)
    f32x4  wq[4][4];    // depth-4 emission prefetch ring
    int    off  = 0;    // accumulated pow2 offset (uniform per column)
    int    eref = 0;    // exponent of previous state's column max

    #define PREF(slot, t) do {                                         \
        const float* _p = ebase + (t) * NTAG + 4 * g;                  \
        wq[slot][0] = *(const f32x4*)(_p +  0);                        \
        wq[slot][1] = *(const f32x4*)(_p + 16);                        \
        wq[slot][2] = *(const f32x4*)(_p + 32);                        \
        wq[slot][3] = *(const f32x4*)(_p + 48);                        \
    } while (0)

    // B operand kt = concat(Bf[2kt], Bf[2kt+1]) under rho (see header).
    #define BCAT(i) __builtin_bit_cast(s16x8,                          \
        (u32x4){Bf[2*(i)].x, Bf[2*(i)].y, Bf[2*(i)+1].x, Bf[2*(i)+1].y})

    #define MFMA_ALL() do {                                            \
        s16x8 B0 = BCAT(0), B1 = BCAT(1);                              \
        f32x4 a0 = {0.f,0.f,0.f,0.f}, a1 = a0, a2 = a0, a3 = a0;       \
        a0 = mfma32(Af[0][0], B0, a0);                                 \
        a1 = mfma32(Af[1][0], B0, a1);                                 \
        a2 = mfma32(Af[2][0], B0, a2);                                 \
        a3 = mfma32(Af[3][0], B0, a3);                                 \
        a0 = mfma32(Af[0][1], B1, a0);                                 \
        a1 = mfma32(Af[1][1], B1, a1);                                 \
        a2 = mfma32(Af[2][1], B1, a2);                                 \
        a3 = mfma32(Af[3][1], B1, a3);                                 \
        ym[0] = a0; ym[1] = a1; ym[2] = a2; ym[3] = a3;                \
    } while (0)

    // Column max across the 4 lanes of column c (xor-16/32 keep c, vary g).
    // Guard ef==0 (all-zero, impossible but safe) and ef==0xff (inf/nan).
    #define COLMAX_UPDATE(mxv) do {                                    \
        float _m = (mxv);                                              \
        _m = fmaxf(_m, __shfl_xor(_m, 16, 64));                        \
        _m = fmaxf(_m, __shfl_xor(_m, 32, 64));                        \
        const int _ef = (int)((__float_as_uint(_m) >> 23) & 0xffu);    \
        eref = (_ef == 0 || _ef == 0xff) ? 0 : _ef - 127;              \
    } while (0)

    #define STEP_W(slot) do {                                          \
        const float fne = (float)(-eref);                              \
        off += eref;                                                   \
        MFMA_ALL();                                                    \
        float mx = 0.f;                                                \
        _Pragma("unroll")                                              \
        for (int m = 0; m < 4; ++m) {                                  \
            _Pragma("unroll")                                          \
            for (int j = 0; j < 4; ++j) {                              \
                ym[m][j] *= EXP2(fmaf(wq[slot][m][j], L2E, fne));      \
                mx = fmaxf(mx, ym[m][j]);                              \
            }                                                          \
            Bf[m].x = cvtpk_bf16(ym[m][0], ym[m][1]);                  \
            Bf[m].y = cvtpk_bf16(ym[m][2], ym[m][3]);                  \
        }                                                              \
        COLMAX_UPDATE(mx);                                             \
    } while (0)

    #define STEP_BARE() do {                                           \
        off += eref;                                                   \
        const float rs = __uint_as_float((unsigned)(127 - eref) << 23);\
        MFMA_ALL();                                                    \
        _Pragma("unroll")                                              \
        for (int m = 0; m < 4; ++m) ym[m] = ym[m] * rs;                \
    } while (0)

    if (w == 0) {
        // seed alpha_0 = indicator(START=62): row 62 = 16*3+4*3+2 -> Bf[3].y lo
        Bf[0].x = 0u; Bf[0].y = 0u; Bf[1] = Bf[0]; Bf[2] = Bf[0];
        Bf[3].x = 0u; Bf[3].y = (g == 3) ? 0x3f80u : 0u;
        eref = 0;   // seed column max = 1.0 -> exponent 0 (exact)

        PREF(0, 0); PREF(1, 1); PREF(2, 2); PREF(3, 3);
        #pragma clang loop unroll(disable)
        for (int it = 0; it < 63; ++it) {
            const int t = it * 4;
            STEP_W(0); PREF(0, t + 4);
            STEP_W(1); PREF(1, t + 5);
            STEP_W(2); PREF(2, t + 6);
            STEP_W(3); PREF(3, t + 7);
        }
        STEP_W(0); STEP_W(1); STEP_W(2); STEP_W(3);   // t = 252..255
        // ym = alpha_255 * 2^-off (f32)
    } else {
        // seed z_511[r][c] = exp(trans[STOP][r] + emis[c][511][r])
        float smx = 0.f;
        #pragma unroll
        for (int m = 0; m < 4; ++m) {
            const float* _p = ebase + 511 * NTAG + 16 * m + 4 * g;
            f32x4 wv = *(const f32x4*)_p;
            float v[4];
            #pragma unroll
            for (int j = 0; j < 4; ++j) {
                const int r = 16 * m + 4 * g + j;
                v[j] = EXP2((trans[STOP_TAG * NTAG + r] + wv[j]) * L2E);
                smx = fmaxf(smx, v[j]);
            }
            Bf[m].x = cvtpk_bf16(v[0], v[1]);
            Bf[m].y = cvtpk_bf16(v[2], v[3]);
        }
        COLMAX_UPDATE(smx);

        PREF(0, 510); PREF(1, 509); PREF(2, 508); PREF(3, 507);
        #pragma clang loop unroll(disable)
        for (int it = 0; it < 63; ++it) {
            const int t = 510 - it * 4;
            STEP_W(0); PREF(0, t - 4);
            STEP_W(1); PREF(1, t - 5);
            STEP_W(2); PREF(2, t - 6);
            STEP_W(3); PREF(3, t - 7);
        }
        STEP_W(0); STEP_W(1); STEP_W(2);   // t = 258, 257, 256
        STEP_BARE();                       // beta_255 = E^T z_256 (scaled)

        #pragma unroll
        for (int m = 0; m < 4; ++m)
            #pragma unroll
            for (int j = 0; j < 4; ++j)
                fy[lane][4 * m + j] = ym[m][j];
        if (lane < 16) offb_sh[lane] = off;
    }

    __syncthreads();

    if (w == 0) {
        // logZ_c = ln2 * ( log2( sum_r alpha[r][c]*beta[r][c] ) + off_f + off_b )
        float p = 0.f;
        #pragma unroll
        for (int m = 0; m < 4; ++m)
            #pragma unroll
            for (int j = 0; j < 4; ++j)
                p = fmaf(ym[m][j], fy[lane][4 * m + j], p);
        p += __shfl_xor(p, 16, 64);
        p += __shfl_xor(p, 32, 64);
        if (lane < 16)
            out[b0 + lane] = LN2 * (log2f(p) + (float)(off + offb_sh[lane]));
    }

    #undef PREF
    #undef BCAT
    #undef MFMA_ALL
    #undef COLMAX_UPDATE
    #undef STEP_W
    #undef STEP_BARE
}

extern "C" void kernel_launch(void* const* d_in, const int* in_sizes, int n_in,
                              void* d_out, int out_size, void* d_ws, size_t ws_size,
                              hipStream_t stream) {
    const float* emis  = (const float*)d_in[0];   // [512, 512, 64] f32
    const float* trans = (const float*)d_in[1];   // [64, 64] f32
    float* out = (float*)d_out;                   // [512] f32
    (void)in_sizes; (void)n_in; (void)out_size; (void)d_ws; (void)ws_size;
    crf_fwd_bwd<<<512 / NB, 128, 0, stream>>>(emis, trans, out);
}